// Round 13
// baseline (29.434 us; speedup 1.0000x reference)
//
#include <hip/hip_runtime.h>
#include <math.h>

#define N_ELEM 8388608
#define MLE_EPS 1e-5f
#define BLOCK 256
#define NBLOCKS 2048          // 524288 threads x 16 elements

typedef float f32x4 __attribute__((ext_vector_type(4)));
typedef float f32x2 __attribute__((ext_vector_type(2)));
typedef int   i32x2 __attribute__((ext_vector_type(2)));

// Abramowitz-Stegun 7.1.26 erfc: abs error <= 1.5e-7.
__device__ __forceinline__ float fast_erfc(float x) {
    float ax = __builtin_fabsf(x);
    float t  = __builtin_amdgcn_rcpf(__builtin_fmaf(0.3275911f, ax, 1.0f));
    float p  = 1.061405429f;
    p = __builtin_fmaf(p, t, -1.453152027f);
    p = __builtin_fmaf(p, t,  1.421413741f);
    p = __builtin_fmaf(p, t, -0.284496736f);
    p = __builtin_fmaf(p, t,  0.254829592f);
    p = p * t;
    float e = __expf(-ax * ax);
    float r = p * e;
    return (x < 0.0f) ? (2.0f - r) : r;
}

__device__ __forceinline__ float mle_elem(float mu, float ls, float t, int al) {
    const float inv_sqrt2    = 0.7071067811865476f;
    const float half_log_2pi = 0.9189385332046727f;

    float lx        = __logf(t + MLE_EPS);
    float inv_sigma = __expf(-ls);
    float d         = lx - mu;
    float w         = d * inv_sigma;
    float z         = w * inv_sqrt2;
    float loss_alive = -__logf(__builtin_fmaf(0.5f, fast_erfc(z), MLE_EPS));
    float loss_dead  = lx + ls + half_log_2pi + 0.5f * w * w;
    return al ? loss_alive : loss_dead;
}

// R12 proven body: pair-dense layout + non-temporal loads (no L2 alloc churn;
// reuse lives in L3). Partials stored NT too (8KB, keep out of L2).
__global__ __launch_bounds__(BLOCK, 4) void mle_partial_kernel(
    const float* __restrict__ pred,
    const float* __restrict__ tte,
    const int*   __restrict__ alive,
    float* __restrict__ partials,
    int n2)   // number of pairs (N/2 = 4M)
{
    const f32x4* __restrict__ p4 = (const f32x4*)pred;
    const f32x2* __restrict__ t2 = (const f32x2*)tte;
    const i32x2* __restrict__ a2 = (const i32x2*)alive;

    const int g  = blockIdx.x * BLOCK + threadIdx.x;
    const int NT = NBLOCKS * BLOCK;               // 524288
    float acc = 0.0f;

    if (n2 == 8 * NT) {                           // exact fit (N = 8388608)
        #pragma unroll
        for (int r = 0; r < 8; ++r) {
            const int j = g + r * NT;
            f32x4 p = __builtin_nontemporal_load(&p4[j]);
            f32x2 t = __builtin_nontemporal_load(&t2[j]);
            i32x2 a = __builtin_nontemporal_load(&a2[j]);
            acc += mle_elem(p[0], p[1], t[0], a[0]);
            acc += mle_elem(p[2], p[3], t[1], a[1]);
        }
    } else {
        for (int j = g; j < n2; j += NT) {
            f32x4 p = __builtin_nontemporal_load(&p4[j]);
            f32x2 t = __builtin_nontemporal_load(&t2[j]);
            i32x2 a = __builtin_nontemporal_load(&a2[j]);
            acc += mle_elem(p[0], p[1], t[0], a[0]);
            acc += mle_elem(p[2], p[3], t[1], a[1]);
        }
    }

    #pragma unroll
    for (int off = 32; off > 0; off >>= 1)
        acc += __shfl_down(acc, off);

    __shared__ float wsum[BLOCK / 64];
    if ((threadIdx.x & 63) == 0) wsum[threadIdx.x >> 6] = acc;
    __syncthreads();
    if (threadIdx.x == 0) {
        float s = 0.0f;
        #pragma unroll
        for (int w = 0; w < BLOCK / 64; ++w) s += wsum[w];
        __builtin_nontemporal_store(s, &partials[blockIdx.x]);
    }
}

// Single-wave finisher: 64 lanes x 8 float4 = 2048 partials; pure shfl
// reduce, no LDS, no barrier -> minimal launch + execution latency.
__global__ __launch_bounds__(64) void mle_final_kernel(
    const f32x4* __restrict__ partials4, float* __restrict__ out)
{
    float acc = 0.0f;
    #pragma unroll
    for (int k = 0; k < 8; ++k) {
        f32x4 v = __builtin_nontemporal_load(&partials4[threadIdx.x + k * 64]);
        acc += (v[0] + v[1]) + (v[2] + v[3]);
    }

    #pragma unroll
    for (int off = 32; off > 0; off >>= 1)
        acc += __shfl_down(acc, off);

    if (threadIdx.x == 0)
        out[0] = acc / (float)N_ELEM;
}

extern "C" void kernel_launch(void* const* d_in, const int* in_sizes, int n_in,
                              void* d_out, int out_size, void* d_ws, size_t ws_size,
                              hipStream_t stream) {
    const float* pred  = (const float*)d_in[0];
    const float* tte   = (const float*)d_in[1];
    const int*   alive = (const int*)d_in[2];
    float* out = (float*)d_out;
    float* partials = (float*)d_ws;

    const int n  = in_sizes[1];
    const int n2 = n >> 1;   // 4M pairs

    mle_partial_kernel<<<NBLOCKS, BLOCK, 0, stream>>>(pred, tte, alive, partials, n2);
    mle_final_kernel<<<1, 64, 0, stream>>>((const f32x4*)partials, out);
}

// Round 14
// 26.980 us; speedup vs baseline: 1.0910x; 1.0910x over previous
//
#include <hip/hip_runtime.h>
#include <math.h>

#define N_ELEM 8388608
#define MLE_EPS 1e-5f
#define BLOCK 256
#define NBLOCKS 2048          // 524288 threads x 16 elements

typedef float f32x4 __attribute__((ext_vector_type(4)));
typedef float f32x2 __attribute__((ext_vector_type(2)));
typedef int   i32x2 __attribute__((ext_vector_type(2)));

// Abramowitz-Stegun 7.1.26 erfc: abs error <= 1.5e-7.
__device__ __forceinline__ float fast_erfc(float x) {
    float ax = __builtin_fabsf(x);
    float t  = __builtin_amdgcn_rcpf(__builtin_fmaf(0.3275911f, ax, 1.0f));
    float p  = 1.061405429f;
    p = __builtin_fmaf(p, t, -1.453152027f);
    p = __builtin_fmaf(p, t,  1.421413741f);
    p = __builtin_fmaf(p, t, -0.284496736f);
    p = __builtin_fmaf(p, t,  0.254829592f);
    p = p * t;
    float e = __expf(-ax * ax);
    float r = p * e;
    return (x < 0.0f) ? (2.0f - r) : r;
}

__device__ __forceinline__ float mle_elem(float mu, float ls, float t, int al) {
    const float inv_sqrt2    = 0.7071067811865476f;
    const float half_log_2pi = 0.9189385332046727f;

    float lx        = __logf(t + MLE_EPS);
    float inv_sigma = __expf(-ls);
    float d         = lx - mu;
    float w         = d * inv_sigma;
    float z         = w * inv_sqrt2;
    float loss_alive = -__logf(__builtin_fmaf(0.5f, fast_erfc(z), MLE_EPS));
    float loss_dead  = lx + ls + half_log_2pi + 0.5f * w * w;
    return al ? loss_alive : loss_dead;
}

// R12 proven structure (exact revert from R13's regression):
// - pair-dense layout: every wave-level load instruction lane-contiguous
// - non-temporal input loads: no L2 allocation churn (reuse lives in L3)
// - plain cached partials store (NT store evicted them -> R13 regression)
// - 256-thread LDS-reduce finisher (64-thread wave finisher was slower)
__global__ __launch_bounds__(BLOCK, 4) void mle_partial_kernel(
    const float* __restrict__ pred,
    const float* __restrict__ tte,
    const int*   __restrict__ alive,
    float* __restrict__ partials,
    int n2)   // number of pairs (N/2 = 4M)
{
    const f32x4* __restrict__ p4 = (const f32x4*)pred;
    const f32x2* __restrict__ t2 = (const f32x2*)tte;
    const i32x2* __restrict__ a2 = (const i32x2*)alive;

    const int g  = blockIdx.x * BLOCK + threadIdx.x;
    const int NT = NBLOCKS * BLOCK;               // 524288
    float acc = 0.0f;

    if (n2 == 8 * NT) {                           // exact fit (N = 8388608)
        #pragma unroll
        for (int r = 0; r < 8; ++r) {
            const int j = g + r * NT;
            f32x4 p = __builtin_nontemporal_load(&p4[j]);
            f32x2 t = __builtin_nontemporal_load(&t2[j]);
            i32x2 a = __builtin_nontemporal_load(&a2[j]);
            acc += mle_elem(p[0], p[1], t[0], a[0]);
            acc += mle_elem(p[2], p[3], t[1], a[1]);
        }
    } else {
        for (int j = g; j < n2; j += NT) {
            f32x4 p = __builtin_nontemporal_load(&p4[j]);
            f32x2 t = __builtin_nontemporal_load(&t2[j]);
            i32x2 a = __builtin_nontemporal_load(&a2[j]);
            acc += mle_elem(p[0], p[1], t[0], a[0]);
            acc += mle_elem(p[2], p[3], t[1], a[1]);
        }
    }

    #pragma unroll
    for (int off = 32; off > 0; off >>= 1)
        acc += __shfl_down(acc, off);

    __shared__ float wsum[BLOCK / 64];
    if ((threadIdx.x & 63) == 0) wsum[threadIdx.x >> 6] = acc;
    __syncthreads();
    if (threadIdx.x == 0) {
        float s = 0.0f;
        #pragma unroll
        for (int w = 0; w < BLOCK / 64; ++w) s += wsum[w];
        partials[blockIdx.x] = s;
    }
}

__global__ __launch_bounds__(BLOCK) void mle_final_kernel(
    const float4* __restrict__ partials4, float* __restrict__ out)
{
    float acc = 0.0f;
    #pragma unroll
    for (int k = 0; k < 2; ++k) {
        float4 v = partials4[threadIdx.x + k * BLOCK];
        acc += (v.x + v.y) + (v.z + v.w);
    }

    #pragma unroll
    for (int off = 32; off > 0; off >>= 1)
        acc += __shfl_down(acc, off);

    __shared__ float wsum[BLOCK / 64];
    if ((threadIdx.x & 63) == 0) wsum[threadIdx.x >> 6] = acc;
    __syncthreads();
    if (threadIdx.x == 0) {
        float s = 0.0f;
        #pragma unroll
        for (int w = 0; w < BLOCK / 64; ++w) s += wsum[w];
        out[0] = s / (float)N_ELEM;
    }
}

extern "C" void kernel_launch(void* const* d_in, const int* in_sizes, int n_in,
                              void* d_out, int out_size, void* d_ws, size_t ws_size,
                              hipStream_t stream) {
    const float* pred  = (const float*)d_in[0];
    const float* tte   = (const float*)d_in[1];
    const int*   alive = (const int*)d_in[2];
    float* out = (float*)d_out;
    float* partials = (float*)d_ws;

    const int n  = in_sizes[1];
    const int n2 = n >> 1;   // 4M pairs

    mle_partial_kernel<<<NBLOCKS, BLOCK, 0, stream>>>(pred, tte, alive, partials, n2);
    mle_final_kernel<<<1, BLOCK, 0, stream>>>((const float4*)partials, out);
}